// Round 1
// baseline (266.715 us; speedup 1.0000x reference)
//
#include <hip/hip_runtime.h>

// Output layout (flat, reference return order), N=64, B=16, D=512:
//   [0,       mapsz)          boundary [B,D,N,N]
//   [mapsz, 2*mapsz)          content  [B,D,N,N]
//   [2*mapsz, 2*mapsz+B*N*N)  mask     [B,1,N,N] (0.0/1.0 f32)
//
// Identities (verified R1/R2): on member lines content[i,j] = max(x[i..j]),
// boundary[i,j] = 0.5*(x[i]+x[j]); the diagonal is the len=1 case of both.
//
// R3 structure: one wave covers FOUR 64x64 tiles; each 16-lane subgroup owns
// one tile, each lane owns 4 consecutive columns -> all stores are
// global_store_dwordx4 (1 KB/wave-instr, 4x the bytes-in-flight of the
// previous dword stores; nontemporal since the 268 MB output is never
// re-read and is 8x L2). The whole 256 B tile row is broadcast-loaded into
// 64 registers (constant-indexed after full unroll), eliminating all shfl.

typedef float f32x4 __attribute__((ext_vector_type(4)));

__global__ __launch_bounds__(256) void sbc_kernel(const float* __restrict__ x,
                                                  float* __restrict__ out,
                                                  size_t mapsz) {
    const int lane = threadIdx.x & 63;
    const int wid  = blockIdx.x * 4 + (threadIdx.x >> 6);   // wave id
    const int g    = lane >> 4;          // which of the wave's 4 tiles
    const int t    = lane & 15;          // lane within the tile's 16
    const int j0   = t * 4;              // first of this lane's 4 columns
    const int tile = wid * 4 + g;

    const float* xt = x + (size_t)tile * 64;

    // Broadcast-load the tile's 64 x-values into registers. All 16 lanes of
    // a subgroup present the same address per instruction (4 distinct 16 B
    // segments per wave) -> one L1 access serves the group. Every index
    // below is compile-time after unrolling, so xall[] stays in VGPRs.
    float xall[64];
#pragma unroll
    for (int k = 0; k < 16; ++k) {
        f32x4 v = *(const f32x4*)(xt + 4 * k);
        xall[4 * k + 0] = v[0];
        xall[4 * k + 1] = v[1];
        xall[4 * k + 2] = v[2];
        xall[4 * k + 3] = v[3];
    }
    // This lane's own 4 column values (distributed coalesced load, L1-hot).
    const f32x4 xj = *(const f32x4*)(xt + j0);

    // Membership bitmask per owned column j (bit i set iff (i,j) on the mask):
    //  diag: i==j
    //  g0: off=j-i in 1..15, any i          (rev const: bits 48..62)
    //  g1: off odd in 17..31, i even        (rev const: bits 32,34..46, & even-i)
    //  g2: off%4==3 in 35..63, i%4==0       (rev const: bits 0,4..28,  & i%4==0)
    unsigned long long mb[4];
#pragma unroll
    for (int c = 0; c < 4; ++c) {
        const int j  = j0 + c;
        const int sh = 63 - j;
        mb[c] = (1ULL << j)
              | (0x7FFF000000000000ULL >> sh)
              | ((0x0000555500000000ULL >> sh) & 0x5555555555555555ULL)
              | ((0x0000000011111111ULL >> sh) & 0x1111111111111111ULL);
    }

    const f32x4 xj05 = xj * 0.5f;
    float r[4];   // running max of x[i..j] per owned column; finite init
#pragma unroll
    for (int c = 0; c < 4; ++c) r[c] = xj[c];

    float* __restrict__ bout = out + (size_t)tile * 4096 + j0;
    float* __restrict__ cout = bout + mapsz;

#pragma unroll
    for (int i = 63; i >= 0; --i) {
        const float xi   = xall[i];          // register (constant index)
        const float xi05 = xi * 0.5f;
        f32x4 bv, cv;
#pragma unroll
        for (int c = 0; c < 4; ++c) {
            const int j = j0 + c;
            // running max of x[i..j], only once i enters [0, j]
            const float xs = (j >= i) ? xi : -INFINITY;
            r[c] = fmaxf(r[c], xs);
            const bool on = (mb[c] >> i) & 1ULL;
            bv[c] = on ? (xi05 + xj05[c]) : 0.0f;
            cv[c] = on ? r[c] : 0.0f;
        }
        __builtin_nontemporal_store(bv, (f32x4*)(bout + i * 64));
        __builtin_nontemporal_store(cv, (f32x4*)(cout + i * 64));
    }

    // mask: one copy per batch, owned by subgroup 0 of every 128th wave
    // (tile = wid*4 divisible by 512 <=> wid % 128 == 0, g == 0)
    if (g == 0 && (wid & 127) == 0) {
        float* __restrict__ mout = out + 2 * mapsz + (size_t)(wid >> 7) * 4096 + j0;
#pragma unroll
        for (int i = 0; i < 64; ++i) {
            f32x4 mv;
#pragma unroll
            for (int c = 0; c < 4; ++c)
                mv[c] = ((mb[c] >> i) & 1ULL) ? 1.0f : 0.0f;
            __builtin_nontemporal_store(mv, (f32x4*)(mout + i * 64));
        }
    }
}

extern "C" void kernel_launch(void* const* d_in, const int* in_sizes, int n_in,
                              void* d_out, int out_size, void* d_ws, size_t ws_size,
                              hipStream_t stream) {
    const float* x = (const float*)d_in[0];
    float* out = (float*)d_out;
    const int N  = 64;
    const int BD = in_sizes[0] / N;                   // 8192 tiles
    const size_t mapsz = (size_t)BD * N * N;          // 33,554,432
    const int nwaves = BD / 4;                        // 2048 (4 tiles/wave)
    sbc_kernel<<<dim3(nwaves / 4), dim3(256), 0, stream>>>(x, out, mapsz);
}

// Round 3
// 256.160 us; speedup vs baseline: 1.0412x; 1.0412x over previous
//
#include <hip/hip_runtime.h>

// Output layout (flat, reference return order), N=64, B=16, D=512:
//   [0,       mapsz)          boundary [B,D,N,N]
//   [mapsz, 2*mapsz)          content  [B,D,N,N]
//   [2*mapsz, 2*mapsz+B*N*N)  mask     [B,1,N,N] (0.0/1.0 f32)
//
// Identities (verified in prior session): on member lines
// content[i,j] = max(x[i..j]), boundary[i,j] = 0.5*(x[i]+x[j]).
//
// Structure: ONE tile per wave (8192 waves, fully resident), lane owns
// (row-offset g = lane>>4, columns j0..j0+3, j0 = (lane&15)*4). Per step s
// the wave stores rows 4s..4s+3 = 1 KB contiguous per map as dwordx4
// (normal stores -- the 6.5 TB/s fill path). Cross-lane row values come
// from 4 ds_bpermute per step (LDS pipe, otherwise idle); no register
// broadcast array, keeping VGPRs low for full 8-wave/SIMD occupancy.
//
// Max recurrence with row stride 4: at the unique "entry" step sE[c] where
// i first drops to <= j, set r = prefix-max P_tE (tE = (j-g)&3); at later
// steps accumulate r = max(r, max(x[i..i+3])) unpredicated -- provably all
// indices <= j there. Pre-entry r is garbage but never read (cv masked 0).

typedef float f32x4 __attribute__((ext_vector_type(4)));

__global__ __launch_bounds__(256) void sbc_kernel(const float* __restrict__ x,
                                                  float* __restrict__ out,
                                                  size_t mapsz) {
    const int lane = threadIdx.x & 63;
    const int wid  = blockIdx.x * 4 + (threadIdx.x >> 6);
    const int g    = lane >> 4;          // row offset within each 4-row block
    const int j0   = (lane & 15) * 4;    // first owned column
    const int tile = wid;

    const float* xt = x + (size_t)tile * 64;
    const float xv = xt[lane];                     // coalesced 256 B/wave
    const f32x4 xj = *(const f32x4*)(xt + j0);     // owned columns (L1-hot)

    // Per-column constants: membership-per-step (on16), entry step (sE),
    // entry prefix length (tE), halved column value.
    unsigned on16[4];
    int sE[4], tE[4];
    f32x4 hxj;
#pragma unroll
    for (int c = 0; c < 4; ++c) {
        const int j  = j0 + c;
        const int sh = 63 - j;
        const unsigned long long mb =
              (1ULL << j)
            | (0x7FFF000000000000ULL >> sh)
            | ((0x0000555500000000ULL >> sh) & 0x5555555555555555ULL)
            | ((0x0000000011111111ULL >> sh) & 0x1111111111111111ULL);
        // compact bits {g, g+4, ..., g+60} of mb into 16 step bits
        unsigned long long v = (mb >> g) & 0x1111111111111111ULL;
        v |= v >> 3;  v &= 0x0303030303030303ULL;
        v |= v >> 6;  v &= 0x000F000F000F000FULL;
        v |= v >> 12; v &= 0x000000FF000000FFULL;
        v |= v >> 24;
        on16[c] = (unsigned)v & 0xFFFFu;
        const int d = j - g;     // may be negative: entry never fires
        sE[c] = d >> 2;          // arithmetic shift
        tE[c] = d & 3;
        hxj[c] = 0.5f * xj[c];
    }

    float r[4];
#pragma unroll
    for (int c = 0; c < 4; ++c) r[c] = xj[c];   // pre-entry value irrelevant

    float* __restrict__ b0 = out + (size_t)tile * 4096 + g * 64 + j0;
    float* __restrict__ c0 = b0 + mapsz;

#pragma unroll
    for (int s = 15; s >= 0; --s) {
        const int i = 4 * s + g;                 // this lane's row
        // x[i..i+3] via bpermute; index wraps (&63) only pre-entry -> harmless
        const float y0 = __shfl(xv, i, 64);
        const float y1 = __shfl(xv, i + 1, 64);
        const float y2 = __shfl(xv, i + 2, 64);
        const float y3 = __shfl(xv, i + 3, 64);
        const float P1 = fmaxf(y0, y1);
        const float P2 = fmaxf(P1, y2);
        const float P3 = fmaxf(P2, y3);
        const float xi05 = 0.5f * y0;
        f32x4 bv, cv;
#pragma unroll
        for (int c = 0; c < 4; ++c) {
            const float pick = tE[c] >= 3 ? P3
                             : (tE[c] == 2 ? P2 : (tE[c] == 1 ? P1 : y0));
            const float rn = fmaxf(r[c], P3);
            r[c] = (s == sE[c]) ? pick : rn;     // reset at entry, else accum
            const bool on = (on16[c] >> s) & 1u;
            bv[c] = on ? (xi05 + hxj[c]) : 0.0f;
            cv[c] = on ? r[c] : 0.0f;
        }
        *(f32x4*)(b0 + s * 256) = bv;            // rows 4s..4s+3, 1 KB/wave
        *(f32x4*)(c0 + s * 256) = cv;
    }

    // mask: one copy per batch, owned by the wave with d==0 (tile%512==0)
    if ((wid & 511) == 0) {
        float* __restrict__ m0 = out + 2 * mapsz + (size_t)(wid >> 9) * 4096
                               + g * 64 + j0;
#pragma unroll
        for (int s = 0; s < 16; ++s) {
            f32x4 mv;
#pragma unroll
            for (int c = 0; c < 4; ++c)
                mv[c] = ((on16[c] >> s) & 1u) ? 1.0f : 0.0f;
            *(f32x4*)(m0 + s * 256) = mv;
        }
    }
}

extern "C" void kernel_launch(void* const* d_in, const int* in_sizes, int n_in,
                              void* d_out, int out_size, void* d_ws, size_t ws_size,
                              hipStream_t stream) {
    const float* x = (const float*)d_in[0];
    float* out = (float*)d_out;
    const int N  = 64;
    const int BD = in_sizes[0] / N;                   // 8192 tiles
    const size_t mapsz = (size_t)BD * N * N;          // 33,554,432
    sbc_kernel<<<dim3(BD / 4), dim3(256), 0, stream>>>(x, out, mapsz);
}